// Round 6
// baseline (23.888 us; speedup 1.0000x reference)
//
#include <hip/hip_runtime.h>
#include <math.h>

// HungarianMatcher cost matrix:
//   C[i,j] = 5*L1(pred_box_i, tgt_box_j) + 2*(pos-neg focal at tgt class j) - 2*GIoU
// Shapes: pred_logits [BN,NC], pred_boxes [BN,4], tgt_ids [NT], tgt_bbox [NT,4]
// BN=16*900=14400, NC=91, NT=960. Output [BN,NT] fp32.
//
// R6: writes are L3-absorbed (54MB < 256MB) -> kernel is VALU/latency bound.
// Class table stored class-major [class][4 rows]; per thread 4x ds_read_b128
// prefetched right after the barrier -> main loop is pure VALU + stores.

#define ALPHA_F   0.25f
#define COST_CLS  2.0f
#define COST_BBOX 5.0f
#define COST_GIOU 2.0f
#define EPS_F     1e-8f

constexpr int THREADS = 256;

// ---------------------- specialized kernel (ROWS = 4) -----------------------
template<int NC, int NT>
__global__ __launch_bounds__(THREADS, 6) void matcher_kernel_s(
    const float* __restrict__ logits,   // [BN, NC]
    const float* __restrict__ boxes,    // [BN, 4] cxcywh
    const int*   __restrict__ tids,     // [NT]
    const float* __restrict__ tboxes,   // [NT, 4] cxcywh
    float*       __restrict__ out)      // [BN, NT]
{
    constexpr int ROWS = 4;
    constexpr int JPT  = 4;                   // contiguous targets per thread
    constexpr int NJT  = NT / JPT;            // 240 active threads
    constexpr int NTAB = ROWS * NC;           // 364 table entries
    constexpr int LPT  = (NTAB + THREADS - 1) / THREADS;   // 2
    constexpr int NCP  = 96;                  // padded class count

    __shared__ float4 s_cls4[NCP];            // [class][4 rows], 1.5 KB
    float* const s_clsf = reinterpret_cast<float*>(s_cls4);

    const int tid  = threadIdx.x;
    const int row0 = blockIdx.x * ROWS;
    const bool active = tid < NJT;

    // ---- issue logits loads first (feeds the exp/log table chain) ----
    const float* __restrict__ lg = logits + (size_t)row0 * NC;
    float lv[LPT];
    #pragma unroll
    for (int i = 0; i < LPT; ++i) {
        const int t = tid + i * THREADS;
        lv[i] = (t < NTAB) ? lg[t] : 0.0f;
    }

    // ---- this thread's 4 targets: derived, row-invariant registers ----
    float tcx[JPT], tcy[JPT], tw[JPT], th[JPT];
    float tx0[JPT], tx1[JPT], ty0[JPT], ty1[JPT], tarea[JPT];
    int   ic[JPT];
    if (active) {
        const int4 tv = reinterpret_cast<const int4*>(tids)[tid];
        ic[0] = tv.x; ic[1] = tv.y; ic[2] = tv.z; ic[3] = tv.w;
        #pragma unroll
        for (int k = 0; k < JPT; ++k) {
            const float4 b = reinterpret_cast<const float4*>(tboxes)[tid * JPT + k];
            tcx[k] = b.x; tcy[k] = b.y; tw[k] = b.z; th[k] = b.w;
            const float hw = 0.5f * b.z, hh = 0.5f * b.w;
            tx0[k] = b.x - hw;  tx1[k] = b.x + hw;
            ty0[k] = b.y - hh;  ty1[k] = b.y + hh;
            tarea[k] = b.z * b.w;
        }
    } else {
        #pragma unroll
        for (int k = 0; k < JPT; ++k) {
            tcx[k]=tcy[k]=tw[k]=th[k]=tx0[k]=tx1[k]=ty0[k]=ty1[k]=tarea[k]=0.f;
            ic[k] = 0;
        }
    }

    // ---- focal class table, class-major layout: s_clsf[c*ROWS + r] ----
    #pragma unroll
    for (int i = 0; i < LPT; ++i) {
        const int t = tid + i * THREADS;
        if (t < NTAB) {
            const float x  = lv[i];
            const float p  = 1.0f / (1.0f + __expf(-x));
            const float om = 1.0f - p;
            const float neg = (1.0f - ALPHA_F) * p * p * (-__logf(om + EPS_F));
            const float pos = ALPHA_F * om * om        * (-__logf(p  + EPS_F));
            const int r = t / NC, c = t - r * NC;
            s_clsf[c * ROWS + r] = pos - neg;
        }
    }
    __syncthreads();   // the only barrier

    if (!active) return;

    // ---- prefetch the 16 class costs as 4x ds_read_b128 (one wait total) ----
    float4 cc[JPT];
    #pragma unroll
    for (int k = 0; k < JPT; ++k)
        cc[k] = s_cls4[ic[k]];

    // ---- hoist all 4 pred-box loads (uniform addr -> s_load, SGPR-resident) ----
    float4 pbv[ROWS];
    #pragma unroll
    for (int r = 0; r < ROWS; ++r)
        pbv[r] = reinterpret_cast<const float4*>(boxes)[row0 + r];

    float* __restrict__ optr = out + (size_t)row0 * NT + tid * JPT;
    #pragma unroll
    for (int r = 0; r < ROWS; ++r) {
        const float4 pb = pbv[r];
        const float px0 = pb.x - 0.5f * pb.z, py0 = pb.y - 0.5f * pb.w;
        const float px1 = pb.x + 0.5f * pb.z, py1 = pb.y + 0.5f * pb.w;
        const float parea = pb.z * pb.w;

        float rv[JPT];
        #pragma unroll
        for (int k = 0; k < JPT; ++k) {
            // L1 in cxcywh space (abs folds into VOP3 src modifiers)
            const float l1 = (fabsf(pb.x - tcx[k]) + fabsf(pb.y - tcy[k]))
                           + (fabsf(pb.z - tw[k])  + fabsf(pb.w - th[k]));
            // raw intersection extents (feed enclosing box too)
            const float iwr = fminf(px1, tx1[k]) - fmaxf(px0, tx0[k]);
            const float ihr = fminf(py1, ty1[k]) - fmaxf(py0, ty0[k]);
            const float inter = fmaxf(iwr, 0.0f) * fmaxf(ihr, 0.0f);
            const float uni = (parea + tarea[k]) - inter;
            // enclosing box via identity: cw = pw + tw - iwr
            const float cw = (pb.z + tw[k]) - iwr;
            const float ch = (pb.w + th[k]) - ihr;
            const float carea = cw * ch;
            // giou = [carea*(inter-uni)+uni^2] / (uni*carea), one rcp
            const float num  = carea * (inter - uni) + uni * uni;
            const float giou = num * __builtin_amdgcn_rcpf(uni * carea);
            // class cost from the prefetched float4 (r is compile-time)
            const float ccls = (r == 0) ? cc[k].x : (r == 1) ? cc[k].y
                             : (r == 2) ? cc[k].z : cc[k].w;
            rv[k] = (COST_BBOX * l1 + COST_CLS * ccls) - COST_GIOU * giou;
        }
        *reinterpret_cast<float4*>(optr) = make_float4(rv[0], rv[1], rv[2], rv[3]);
        optr += NT;
    }
}

// ----------------------------- generic fallback -----------------------------
constexpr int GROWS = 8;
__global__ __launch_bounds__(THREADS) void matcher_kernel_g(
    const float* __restrict__ logits, const float* __restrict__ boxes,
    const int* __restrict__ tids, const float* __restrict__ tboxes,
    float* __restrict__ out, int BN, int NC, int NT)
{
    extern __shared__ float s_cls_g[];
    const int tid  = threadIdx.x;
    const int row0 = blockIdx.x * GROWS;
    const int nrows = (BN - row0 < GROWS) ? (BN - row0) : GROWS;

    for (int t = tid; t < nrows * NC; t += THREADS) {
        const int r = t / NC, c = t - r * NC;
        const float x  = logits[(size_t)(row0 + r) * NC + c];
        const float p  = 1.0f / (1.0f + expf(-x));
        const float om = 1.0f - p;
        const float neg = (1.0f - ALPHA_F) * p * p * (-logf(om + EPS_F));
        const float pos = ALPHA_F * om * om        * (-logf(p + EPS_F));
        s_cls_g[r * NC + c] = pos - neg;
    }
    __syncthreads();

    for (int r = 0; r < nrows; ++r) {
        const int row = row0 + r;
        const float4 pb = reinterpret_cast<const float4*>(boxes)[row];
        const float px0 = pb.x - 0.5f * pb.z, py0 = pb.y - 0.5f * pb.w;
        const float px1 = pb.x + 0.5f * pb.z, py1 = pb.y + 0.5f * pb.w;
        const float parea = pb.z * pb.w;
        for (int j = tid; j < NT; j += THREADS) {
            const float4 b = reinterpret_cast<const float4*>(tboxes)[j];
            const float bx0 = b.x - 0.5f * b.z, by0 = b.y - 0.5f * b.w;
            const float bx1 = b.x + 0.5f * b.z, by1 = b.y + 0.5f * b.w;
            const float l1 = fabsf(pb.x - b.x) + fabsf(pb.y - b.y)
                           + fabsf(pb.z - b.z) + fabsf(pb.w - b.w);
            const float iw = fmaxf(fminf(px1, bx1) - fmaxf(px0, bx0), 0.0f);
            const float ih = fmaxf(fminf(py1, by1) - fmaxf(py0, by0), 0.0f);
            const float inter = iw * ih;
            const float uni = parea + b.z * b.w - inter;
            const float iou = inter / uni;
            const float cw = fmaxf(px1, bx1) - fminf(px0, bx0);
            const float ch = fmaxf(py1, by1) - fminf(py0, by0);
            const float carea = cw * ch;
            const float giou = iou - (carea - uni) / carea;
            const float ccls = s_cls_g[r * NC + tids[j]];
            out[(size_t)row * NT + j] = COST_BBOX * l1 + COST_CLS * ccls - COST_GIOU * giou;
        }
        __syncthreads();
    }
}

extern "C" void kernel_launch(void* const* d_in, const int* in_sizes, int n_in,
                              void* d_out, int out_size, void* d_ws, size_t ws_size,
                              hipStream_t stream) {
    const float* logits = (const float*)d_in[0];
    const float* boxes  = (const float*)d_in[1];
    const int*   tids   = (const int*)d_in[2];
    const float* tboxes = (const float*)d_in[3];
    float* out = (float*)d_out;

    const int BN = in_sizes[1] / 4;       // 14400
    const int NC = in_sizes[0] / BN;      // 91
    const int NT = in_sizes[2];           // 960

    if (NC == 91 && NT == 960 && BN % 4 == 0) {
        const int grid = BN / 4;          // 3600
        matcher_kernel_s<91, 960><<<grid, THREADS, 0, stream>>>(
            logits, boxes, tids, tboxes, out);
    } else {
        const int grid = (BN + GROWS - 1) / GROWS;
        const size_t shmem = (size_t)GROWS * NC * sizeof(float);
        matcher_kernel_g<<<grid, THREADS, shmem, stream>>>(
            logits, boxes, tids, tboxes, out, BN, NC, NT);
    }
}